// Round 1
// baseline (57.005 us; speedup 1.0000x reference)
//
#include <hip/hip_runtime.h>
#include <cstdint>
#include <math.h>

#define NPARTS 4
#define NPTS   8192

// ws layout (bytes):
//   [0, 256)    float transforms[4][16]      (row-major 4x4 per part)
//   [256, 328)  double sums[4][2] + dist_sum (9 doubles)
//   [384, ...)  uint32 minbuf[2][4][8192]    (dir, part, idx) = 256 KiB
#define WS_SUMS_OFF 256
#define WS_MIN_OFF  384

__global__ __launch_bounds__(256) void k_setup(const float* __restrict__ rot_quats,
                                               const float* __restrict__ tras,
                                               float* __restrict__ ws,
                                               float* __restrict__ out) {
    uint32_t* minbuf = (uint32_t*)((char*)ws + WS_MIN_OFF);
    int gid = blockIdx.x * blockDim.x + threadIdx.x;
    int nthr = gridDim.x * blockDim.x;
    for (int i = gid; i < 2 * NPARTS * NPTS; i += nthr) minbuf[i] = 0x7F800000u; // +inf
    if (blockIdx.x == 0) {
        if (threadIdx.x >= 16 && threadIdx.x < 25) {
            double* s = (double*)((char*)ws + WS_SUMS_OFF);
            s[threadIdx.x - 16] = 0.0;
        }
        if (threadIdx.x < NPARTS) {
            int p = threadIdx.x;
            double q0 = rot_quats[p*4+0], q1 = rot_quats[p*4+1];
            double q2 = rot_quats[p*4+2], q3 = rot_quats[p*4+3];
            double inv = 1.0 / sqrt(q0*q0 + q1*q1 + q2*q2 + q3*q3);
            double a = q0*inv, b = q1*inv, c = q2*inv, d = q3*inv;
            float T[16];
            T[0]  = (float)(1.0 - 2.0*c*c - 2.0*d*d);
            T[1]  = (float)(2.0*b*c - 2.0*a*d);
            T[2]  = (float)(2.0*a*c + 2.0*b*d);
            T[3]  = tras[p*3+0];
            T[4]  = (float)(2.0*b*c + 2.0*a*d);
            T[5]  = (float)(1.0 - 2.0*b*b - 2.0*d*d);
            T[6]  = (float)(2.0*c*d - 2.0*a*b);
            T[7]  = tras[p*3+1];
            T[8]  = (float)(2.0*b*d - 2.0*a*c);
            T[9]  = (float)(2.0*a*b + 2.0*c*d);
            T[10] = (float)(1.0 - 2.0*b*b - 2.0*c*c);
            T[11] = tras[p*3+2];
            T[12] = 0.f; T[13] = 0.f; T[14] = 0.f; T[15] = 1.f;
            #pragma unroll
            for (int i = 0; i < 16; ++i) {
                ws[p*16 + i] = T[i];
                out[6 + p*16 + i] = T[i];   // transforms output
            }
        }
    }
}

// Chamfer core: grid = NPARTS * 2(dir) * XTILES * YSPLIT blocks, 256 threads.
// dir 0: x = transformed cad, y = cam   (min over axis=1)
// dir 1: x = cam, y = transformed cad   (min over axis=0)
__global__ __launch_bounds__(256, 2) void k_chamfer(const float* __restrict__ cam,
                                                    const float* __restrict__ cad,
                                                    float* __restrict__ ws) {
    constexpr int TPB = 256, REG_X = 8;
    constexpr int XTILE = TPB * REG_X;        // 2048
    constexpr int XTILES = NPTS / XTILE;      // 4
    constexpr int YSPLIT = 16;
    constexpr int YLEN = NPTS / YSPLIT;       // 512
    __shared__ float4 ybuf[YLEN];             // (-2y0,-2y1,-2y2, |y|^2) : 8 KiB

    uint32_t* minbuf = (uint32_t*)((char*)ws + WS_MIN_OFF);

    int b   = blockIdx.x;
    int ysi = b & (YSPLIT - 1);
    int xt  = (b / YSPLIT) & (XTILES - 1);
    int dir = (b / (YSPLIT * XTILES)) & 1;
    int p   = b / (YSPLIT * XTILES * 2);

    float T[12];
    #pragma unroll
    for (int i = 0; i < 12; ++i) T[i] = ws[p*16 + i];

    const float* xsrc = (dir == 0) ? cad + (size_t)p*NPTS*3 : cam + (size_t)p*NPTS*3;
    const float* ysrc = (dir == 0) ? cam + (size_t)p*NPTS*3 : cad + (size_t)p*NPTS*3;

    // stage this block's y-range into LDS
    for (int j = threadIdx.x; j < YLEN; j += TPB) {
        int yi = ysi * YLEN + j;
        float v0 = ysrc[yi*3+0], v1 = ysrc[yi*3+1], v2 = ysrc[yi*3+2];
        if (dir == 1) {
            float w0 = T[0]*v0 + T[1]*v1 + T[2]*v2 + T[3];
            float w1 = T[4]*v0 + T[5]*v1 + T[6]*v2 + T[7];
            float w2 = T[8]*v0 + T[9]*v1 + T[10]*v2 + T[11];
            v0 = w0; v1 = w1; v2 = w2;
        }
        ybuf[j] = make_float4(-2.f*v0, -2.f*v1, -2.f*v2, v0*v0 + v1*v1 + v2*v2);
    }

    // per-thread x points (REG_X of them)
    float x0[REG_X], x1[REG_X], x2c[REG_X], xsq[REG_X];
    #pragma unroll
    for (int r = 0; r < REG_X; ++r) {
        int xi = xt*XTILE + r*TPB + threadIdx.x;
        float v0 = xsrc[xi*3+0], v1 = xsrc[xi*3+1], v2 = xsrc[xi*3+2];
        if (dir == 0) {
            float w0 = T[0]*v0 + T[1]*v1 + T[2]*v2 + T[3];
            float w1 = T[4]*v0 + T[5]*v1 + T[6]*v2 + T[7];
            float w2 = T[8]*v0 + T[9]*v1 + T[10]*v2 + T[11];
            v0 = w0; v1 = w1; v2 = w2;
        }
        x0[r] = v0; x1[r] = v1; x2c[r] = v2;
        xsq[r] = v0*v0 + v1*v1 + v2*v2;
    }

    float mnA[REG_X], mnB[REG_X];
    #pragma unroll
    for (int r = 0; r < REG_X; ++r) { mnA[r] = INFINITY; mnB[r] = INFINITY; }

    __syncthreads();

    // inner: t = x . (-2y) + |y|^2 ; running min of t  (d2 = |x|^2 + t, added later)
    #pragma unroll 2
    for (int j = 0; j < YLEN; j += 2) {
        float4 ya = ybuf[j];
        float4 yb = ybuf[j+1];
        #pragma unroll
        for (int r = 0; r < REG_X; ++r) {
            float ta = fmaf(x0[r], ya.x, ya.w);
            ta = fmaf(x1[r], ya.y, ta);
            ta = fmaf(x2c[r], ya.z, ta);
            mnA[r] = fminf(mnA[r], ta);
            float tb = fmaf(x0[r], yb.x, yb.w);
            tb = fmaf(x1[r], yb.y, tb);
            tb = fmaf(x2c[r], yb.z, tb);
            mnB[r] = fminf(mnB[r], tb);
        }
    }

    #pragma unroll
    for (int r = 0; r < REG_X; ++r) {
        int xi = xt*XTILE + r*TPB + threadIdx.x;
        float d2 = fmaxf(xsq[r] + fminf(mnA[r], mnB[r]), 0.f);
        atomicMin(&minbuf[(dir*NPARTS + p)*NPTS + xi], __float_as_uint(d2));
    }
}

// paired distance term for E_kin: mean over p,n of ||T.cad - cam|| (w-components cancel)
__global__ __launch_bounds__(256) void k_dist(const float* __restrict__ cam,
                                              const float* __restrict__ cad,
                                              float* __restrict__ ws) {
    int gid = blockIdx.x * 256 + threadIdx.x;       // 0 .. 32767
    int p = gid >> 13;
    float T[12];
    #pragma unroll
    for (int i = 0; i < 12; ++i) T[i] = ws[p*16 + i];
    float v0 = cad[gid*3+0], v1 = cad[gid*3+1], v2 = cad[gid*3+2];
    float w0 = T[0]*v0 + T[1]*v1 + T[2]*v2 + T[3];
    float w1 = T[4]*v0 + T[5]*v1 + T[6]*v2 + T[7];
    float w2 = T[8]*v0 + T[9]*v1 + T[10]*v2 + T[11];
    float d0 = w0 - cam[gid*3+0];
    float d1 = w1 - cam[gid*3+1];
    float d2 = w2 - cam[gid*3+2];
    double local = sqrt((double)(d0*d0 + d1*d1 + d2*d2));

    __shared__ double red[256];
    red[threadIdx.x] = local;
    __syncthreads();
    for (int s = 128; s > 0; s >>= 1) {
        if (threadIdx.x < s) red[threadIdx.x] += red[threadIdx.x + s];
        __syncthreads();
    }
    if (threadIdx.x == 0) {
        double* dist_sum = (double*)((char*)ws + WS_SUMS_OFF) + 8;
        atomicAdd(dist_sum, red[0]);
    }
}

// reduce minbuf -> per (part,dir) sum of sqrt(d2)
__global__ __launch_bounds__(256) void k_reduce(float* __restrict__ ws) {
    uint32_t* minbuf = (uint32_t*)((char*)ws + WS_MIN_OFF);
    double* sums = (double*)((char*)ws + WS_SUMS_OFF);
    int b = blockIdx.x;            // 64 blocks x 1024 entries
    int dir = b >> 5;
    int p = (b >> 3) & 3;
    int base = b * 1024;
    double local = 0.0;
    #pragma unroll
    for (int k = 0; k < 4; ++k) {
        uint32_t bits = minbuf[base + k*256 + threadIdx.x];
        local += sqrt((double)__uint_as_float(bits));
    }
    __shared__ double red[256];
    red[threadIdx.x] = local;
    __syncthreads();
    for (int s = 128; s > 0; s >>= 1) {
        if (threadIdx.x < s) red[threadIdx.x] += red[threadIdx.x + s];
        __syncthreads();
    }
    if (threadIdx.x == 0) atomicAdd(&sums[p*2 + dir], red[0]);
}

__global__ void k_final(const float* __restrict__ pw,
                        const float* __restrict__ rtk,
                        const float* __restrict__ ja,
                        const float* __restrict__ ws,
                        float* __restrict__ out) {
    const double* sums = (const double*)((const char*)ws + WS_SUMS_OFF);
    double eners[NPARTS];
    for (int p = 0; p < NPARTS; ++p)
        eners[p] = 5.0 * ((sums[p*2+0] + sums[p*2+1]) / (double)NPTS);

    double mn = eners[0], mx = eners[0];
    for (int p = 1; p < NPARTS; ++p) { mn = fmin(mn, eners[p]); mx = fmax(mx, eners[p]); }
    double et[NPARTS], etmax = -1e300;
    for (int p = 0; p < NPARTS; ++p) { et[p] = (eners[p] - mn) / (mx - mn + 1e-8); etmax = fmax(etmax, et[p]); }
    double ex[NPARTS], se = 0.0;
    for (int p = 0; p < NPARTS; ++p) { ex[p] = exp(et[p] - etmax); se += ex[p]; }

    double ep[NPARTS], all_obj = 0.0, epmax = -1e300;
    for (int p = 0; p < NPARTS; ++p) {
        double sm = ex[p] / se;
        ep[p] = (double)pw[p] * sm * eners[p];
        all_obj += sm * eners[p];
        epmax = fmax(epmax, ep[p]);
    }

    double distances = sums[8] / (double)(NPARTS * NPTS);

    // Tj_q = rt_k[0] @ T[0] @ ja[0,0];  Tj1_q[j] = rt_k[j+1] @ T[j+1] @ ja[j,1]
    double v[4], Tj[4], ss = 0.0;
    for (int i = 0; i < 4; ++i) {
        v[i] = 0.0;
        for (int k = 0; k < 4; ++k) v[i] += (double)ws[0*16 + i*4 + k] * (double)ja[0*8 + 0*4 + k];
    }
    for (int i = 0; i < 4; ++i) {
        Tj[i] = 0.0;
        for (int k = 0; k < 4; ++k) Tj[i] += (double)rtk[0*16 + i*4 + k] * v[k];
    }
    for (int q = 1; q < NPARTS; ++q) {
        double vv[4], u[4];
        for (int i = 0; i < 4; ++i) {
            vv[i] = 0.0;
            for (int k = 0; k < 4; ++k) vv[i] += (double)ws[q*16 + i*4 + k] * (double)ja[(q-1)*8 + 4 + k];
        }
        for (int i = 0; i < 4; ++i) {
            u[i] = 0.0;
            for (int k = 0; k < 4; ++k) u[i] += (double)rtk[q*16 + i*4 + k] * vv[k];
        }
        for (int i = 0; i < 3; ++i) { double dd = Tj[i] - u[i]; ss += dd * dd; }
    }
    double nrm = sqrt(ss) / (double)NPARTS;
    double e_kin = log(0.1 * nrm + 1.0) + distances;
    double ekt = epmax * e_kin;
    all_obj += ekt;

    out[0] = (float)all_obj;
    for (int p = 0; p < NPARTS; ++p) out[1 + p] = (float)ep[p];
    out[5] = (float)ekt;
}

extern "C" void kernel_launch(void* const* d_in, const int* in_sizes, int n_in,
                              void* d_out, int out_size, void* d_ws, size_t ws_size,
                              hipStream_t stream) {
    const float* cam  = (const float*)d_in[0];
    const float* cad  = (const float*)d_in[1];
    const float* pw   = (const float*)d_in[2];
    const float* rq   = (const float*)d_in[3];
    const float* tras = (const float*)d_in[4];
    const float* rtk  = (const float*)d_in[5];
    const float* ja   = (const float*)d_in[6];
    float* out = (float*)d_out;
    float* ws  = (float*)d_ws;

    hipLaunchKernelGGL(k_setup,   dim3(64),  dim3(256), 0, stream, rq, tras, ws, out);
    hipLaunchKernelGGL(k_chamfer, dim3(512), dim3(256), 0, stream, cam, cad, ws);
    hipLaunchKernelGGL(k_dist,    dim3(128), dim3(256), 0, stream, cam, cad, ws);
    hipLaunchKernelGGL(k_reduce,  dim3(64),  dim3(256), 0, stream, ws);
    hipLaunchKernelGGL(k_final,   dim3(1),   dim3(1),   0, stream, pw, rtk, ja, ws, out);
}

// Round 2
// 55.419 us; speedup vs baseline: 1.0286x; 1.0286x over previous
//
#include <hip/hip_runtime.h>
#include <cstdint>
#include <math.h>

#define NPARTS 4
#define NPTS   8192

// ws layout (bytes):
//   [0, 256)    float transforms[4][16]      (row-major 4x4 per part)
//   [256, 328)  double sums[4][2] + dist_sum (9 doubles)
//   [384, ...)  uint32 minbuf[2][4][8192]    (dir, part, idx) = 256 KiB
#define WS_SUMS_OFF 256
#define WS_MIN_OFF  384

typedef float f32x2 __attribute__((ext_vector_type(2)));
typedef float f32x4 __attribute__((ext_vector_type(4)));

__device__ __forceinline__ f32x2 pk_fma(f32x2 a, f32x2 b, f32x2 c) {
    f32x2 d;
    asm("v_pk_fma_f32 %0, %1, %2, %3" : "=v"(d) : "v"(a), "v"(b), "v"(c));
    return d;
}
__device__ __forceinline__ float min3f(float a, float b, float c) {
    float d;
    asm("v_min3_f32 %0, %1, %2, %3" : "=v"(d) : "v"(a), "v"(b), "v"(c));
    return d;
}

__global__ __launch_bounds__(256) void k_setup(const float* __restrict__ rot_quats,
                                               const float* __restrict__ tras,
                                               float* __restrict__ ws,
                                               float* __restrict__ out) {
    uint32_t* minbuf = (uint32_t*)((char*)ws + WS_MIN_OFF);
    int gid = blockIdx.x * blockDim.x + threadIdx.x;
    int nthr = gridDim.x * blockDim.x;
    for (int i = gid; i < 2 * NPARTS * NPTS; i += nthr) minbuf[i] = 0x7F800000u; // +inf
    if (blockIdx.x == 0) {
        if (threadIdx.x >= 16 && threadIdx.x < 25) {
            double* s = (double*)((char*)ws + WS_SUMS_OFF);
            s[threadIdx.x - 16] = 0.0;
        }
        if (threadIdx.x < NPARTS) {
            int p = threadIdx.x;
            double q0 = rot_quats[p*4+0], q1 = rot_quats[p*4+1];
            double q2 = rot_quats[p*4+2], q3 = rot_quats[p*4+3];
            double inv = 1.0 / sqrt(q0*q0 + q1*q1 + q2*q2 + q3*q3);
            double a = q0*inv, b = q1*inv, c = q2*inv, d = q3*inv;
            float T[16];
            T[0]  = (float)(1.0 - 2.0*c*c - 2.0*d*d);
            T[1]  = (float)(2.0*b*c - 2.0*a*d);
            T[2]  = (float)(2.0*a*c + 2.0*b*d);
            T[3]  = tras[p*3+0];
            T[4]  = (float)(2.0*b*c + 2.0*a*d);
            T[5]  = (float)(1.0 - 2.0*b*b - 2.0*d*d);
            T[6]  = (float)(2.0*c*d - 2.0*a*b);
            T[7]  = tras[p*3+1];
            T[8]  = (float)(2.0*b*d - 2.0*a*c);
            T[9]  = (float)(2.0*a*b + 2.0*c*d);
            T[10] = (float)(1.0 - 2.0*b*b - 2.0*c*c);
            T[11] = tras[p*3+2];
            T[12] = 0.f; T[13] = 0.f; T[14] = 0.f; T[15] = 1.f;
            #pragma unroll
            for (int i = 0; i < 16; ++i) {
                ws[p*16 + i] = T[i];
                out[6 + p*16 + i] = T[i];   // transforms output
            }
        }
    }
}

// Chamfer core: 4 parts x 2 dirs x 4 xtiles x 32 ysplits = 1024 blocks (4/CU).
// dir 0: x = transformed cad, y = cam   (min over axis=1)
// dir 1: x = cam, y = transformed cad   (min over axis=0)
// inner math: t = x.(-2y) + |y|^2, packed 2 y's per v_pk_fma_f32;
//             mn = v_min3(mn, t.lo, t.hi); d2 = |x|^2 + mn at the end.
__global__ __launch_bounds__(256, 4) void k_chamfer(const float* __restrict__ cam,
                                                    const float* __restrict__ cad,
                                                    float* __restrict__ ws) {
    constexpr int TPB = 256, REG_X = 8;
    constexpr int XTILE = TPB * REG_X;        // 2048
    constexpr int XTILES = NPTS / XTILE;      // 4
    constexpr int YSPLIT = 32;
    constexpr int YLEN = NPTS / YSPLIT;       // 256
    // SoA y-tile: [comp 0..2 scaled by -2, comp 3 = |y|^2], grouped in float4
    __shared__ f32x4 ybuf4[4][YLEN / 4];      // 4 KiB

    uint32_t* minbuf = (uint32_t*)((char*)ws + WS_MIN_OFF);

    int b   = blockIdx.x;
    int ysi = b & (YSPLIT - 1);
    int xt  = (b / YSPLIT) & (XTILES - 1);
    int dir = (b / (YSPLIT * XTILES)) & 1;
    int p   = b / (YSPLIT * XTILES * 2);

    float T[12];
    #pragma unroll
    for (int i = 0; i < 12; ++i) T[i] = ws[p*16 + i];

    const float* xsrc = (dir == 0) ? cad + (size_t)p*NPTS*3 : cam + (size_t)p*NPTS*3;
    const float* ysrc = (dir == 0) ? cam + (size_t)p*NPTS*3 : cad + (size_t)p*NPTS*3;

    // stage this block's y-range into LDS (1 point per thread)
    {
        int j = threadIdx.x;
        int yi = ysi * YLEN + j;
        float v0 = ysrc[yi*3+0], v1 = ysrc[yi*3+1], v2 = ysrc[yi*3+2];
        if (dir == 1) {
            float w0 = T[0]*v0 + T[1]*v1 + T[2]*v2 + T[3];
            float w1 = T[4]*v0 + T[5]*v1 + T[6]*v2 + T[7];
            float w2 = T[8]*v0 + T[9]*v1 + T[10]*v2 + T[11];
            v0 = w0; v1 = w1; v2 = w2;
        }
        ((float*)ybuf4[0])[j] = -2.f * v0;
        ((float*)ybuf4[1])[j] = -2.f * v1;
        ((float*)ybuf4[2])[j] = -2.f * v2;
        ((float*)ybuf4[3])[j] = v0*v0 + v1*v1 + v2*v2;
    }

    // per-thread x points, broadcast into both packed halves
    f32x2 x0pk[REG_X], x1pk[REG_X], x2pk[REG_X];
    #pragma unroll
    for (int r = 0; r < REG_X; ++r) {
        int xi = xt*XTILE + r*TPB + threadIdx.x;
        float v0 = xsrc[xi*3+0], v1 = xsrc[xi*3+1], v2 = xsrc[xi*3+2];
        if (dir == 0) {
            float w0 = T[0]*v0 + T[1]*v1 + T[2]*v2 + T[3];
            float w1 = T[4]*v0 + T[5]*v1 + T[6]*v2 + T[7];
            float w2 = T[8]*v0 + T[9]*v1 + T[10]*v2 + T[11];
            v0 = w0; v1 = w1; v2 = w2;
        }
        x0pk[r] = (f32x2){v0, v0};
        x1pk[r] = (f32x2){v1, v1};
        x2pk[r] = (f32x2){v2, v2};
    }

    float mn[REG_X];
    #pragma unroll
    for (int r = 0; r < REG_X; ++r) mn[r] = INFINITY;

    __syncthreads();

    for (int g = 0; g < YLEN / 4; ++g) {
        f32x4 c0 = ybuf4[0][g];
        f32x4 c1 = ybuf4[1][g];
        f32x4 c2 = ybuf4[2][g];
        f32x4 qq = ybuf4[3][g];
        f32x2 c0lo = __builtin_shufflevector(c0, c0, 0, 1), c0hi = __builtin_shufflevector(c0, c0, 2, 3);
        f32x2 c1lo = __builtin_shufflevector(c1, c1, 0, 1), c1hi = __builtin_shufflevector(c1, c1, 2, 3);
        f32x2 c2lo = __builtin_shufflevector(c2, c2, 0, 1), c2hi = __builtin_shufflevector(c2, c2, 2, 3);
        f32x2 qqlo = __builtin_shufflevector(qq, qq, 0, 1), qqhi = __builtin_shufflevector(qq, qq, 2, 3);
        #pragma unroll
        for (int r = 0; r < REG_X; ++r) {
            f32x2 t = pk_fma(x0pk[r], c0lo, qqlo);
            t = pk_fma(x1pk[r], c1lo, t);
            t = pk_fma(x2pk[r], c2lo, t);
            mn[r] = min3f(mn[r], t.x, t.y);
            f32x2 u = pk_fma(x0pk[r], c0hi, qqhi);
            u = pk_fma(x1pk[r], c1hi, u);
            u = pk_fma(x2pk[r], c2hi, u);
            mn[r] = min3f(mn[r], u.x, u.y);
        }
    }

    #pragma unroll
    for (int r = 0; r < REG_X; ++r) {
        int xi = xt*XTILE + r*TPB + threadIdx.x;
        float v0 = x0pk[r].x, v1 = x1pk[r].x, v2 = x2pk[r].x;
        float d2 = fmaxf(v0*v0 + v1*v1 + v2*v2 + mn[r], 0.f);
        atomicMin(&minbuf[(dir*NPARTS + p)*NPTS + xi], __float_as_uint(d2));
    }
}

// blocks 0..63: reduce minbuf -> per (part,dir) sum of sqrt(d2)
// blocks 64..191: paired distance term for E_kin (w-components cancel)
__global__ __launch_bounds__(256) void k_reduce(const float* __restrict__ cam,
                                                const float* __restrict__ cad,
                                                float* __restrict__ ws) {
    __shared__ double red[256];
    double local = 0.0;
    int b = blockIdx.x;
    if (b < 64) {
        uint32_t* minbuf = (uint32_t*)((char*)ws + WS_MIN_OFF);
        int base = b * 1024;
        #pragma unroll
        for (int k = 0; k < 4; ++k) {
            uint32_t bits = minbuf[base + k*256 + threadIdx.x];
            local += sqrt((double)__uint_as_float(bits));
        }
        red[threadIdx.x] = local;
        __syncthreads();
        for (int s = 128; s > 0; s >>= 1) {
            if (threadIdx.x < s) red[threadIdx.x] += red[threadIdx.x + s];
            __syncthreads();
        }
        if (threadIdx.x == 0) {
            double* sums = (double*)((char*)ws + WS_SUMS_OFF);
            int dir = b >> 5;
            int p = (b >> 3) & 3;
            atomicAdd(&sums[p*2 + dir], red[0]);
        }
    } else {
        int gid = (b - 64) * 256 + threadIdx.x;   // 0 .. 32767
        int p = gid >> 13;
        float T[12];
        #pragma unroll
        for (int i = 0; i < 12; ++i) T[i] = ws[p*16 + i];
        float v0 = cad[gid*3+0], v1 = cad[gid*3+1], v2 = cad[gid*3+2];
        float w0 = T[0]*v0 + T[1]*v1 + T[2]*v2 + T[3];
        float w1 = T[4]*v0 + T[5]*v1 + T[6]*v2 + T[7];
        float w2 = T[8]*v0 + T[9]*v1 + T[10]*v2 + T[11];
        float d0 = w0 - cam[gid*3+0];
        float d1 = w1 - cam[gid*3+1];
        float d2 = w2 - cam[gid*3+2];
        local = sqrt((double)(d0*d0 + d1*d1 + d2*d2));
        red[threadIdx.x] = local;
        __syncthreads();
        for (int s = 128; s > 0; s >>= 1) {
            if (threadIdx.x < s) red[threadIdx.x] += red[threadIdx.x + s];
            __syncthreads();
        }
        if (threadIdx.x == 0) {
            double* dist_sum = (double*)((char*)ws + WS_SUMS_OFF) + 8;
            atomicAdd(dist_sum, red[0]);
        }
    }
}

__global__ void k_final(const float* __restrict__ pw,
                        const float* __restrict__ rtk,
                        const float* __restrict__ ja,
                        const float* __restrict__ ws,
                        float* __restrict__ out) {
    const double* sums = (const double*)((const char*)ws + WS_SUMS_OFF);
    double eners[NPARTS];
    for (int p = 0; p < NPARTS; ++p)
        eners[p] = 5.0 * ((sums[p*2+0] + sums[p*2+1]) / (double)NPTS);

    double mn = eners[0], mx = eners[0];
    for (int p = 1; p < NPARTS; ++p) { mn = fmin(mn, eners[p]); mx = fmax(mx, eners[p]); }
    double et[NPARTS], etmax = -1e300;
    for (int p = 0; p < NPARTS; ++p) { et[p] = (eners[p] - mn) / (mx - mn + 1e-8); etmax = fmax(etmax, et[p]); }
    double ex[NPARTS], se = 0.0;
    for (int p = 0; p < NPARTS; ++p) { ex[p] = exp(et[p] - etmax); se += ex[p]; }

    double ep[NPARTS], all_obj = 0.0, epmax = -1e300;
    for (int p = 0; p < NPARTS; ++p) {
        double sm = ex[p] / se;
        ep[p] = (double)pw[p] * sm * eners[p];
        all_obj += sm * eners[p];
        epmax = fmax(epmax, ep[p]);
    }

    double distances = sums[8] / (double)(NPARTS * NPTS);

    // Tj_q = rt_k[0] @ T[0] @ ja[0,0];  Tj1_q[j] = rt_k[j+1] @ T[j+1] @ ja[j,1]
    double v[4], Tj[4], ss = 0.0;
    for (int i = 0; i < 4; ++i) {
        v[i] = 0.0;
        for (int k = 0; k < 4; ++k) v[i] += (double)ws[0*16 + i*4 + k] * (double)ja[0*8 + 0*4 + k];
    }
    for (int i = 0; i < 4; ++i) {
        Tj[i] = 0.0;
        for (int k = 0; k < 4; ++k) Tj[i] += (double)rtk[0*16 + i*4 + k] * v[k];
    }
    for (int q = 1; q < NPARTS; ++q) {
        double vv[4], u[4];
        for (int i = 0; i < 4; ++i) {
            vv[i] = 0.0;
            for (int k = 0; k < 4; ++k) vv[i] += (double)ws[q*16 + i*4 + k] * (double)ja[(q-1)*8 + 4 + k];
        }
        for (int i = 0; i < 4; ++i) {
            u[i] = 0.0;
            for (int k = 0; k < 4; ++k) u[i] += (double)rtk[q*16 + i*4 + k] * vv[k];
        }
        for (int i = 0; i < 3; ++i) { double dd = Tj[i] - u[i]; ss += dd * dd; }
    }
    double nrm = sqrt(ss) / (double)NPARTS;
    double e_kin = log(0.1 * nrm + 1.0) + distances;
    double ekt = epmax * e_kin;
    all_obj += ekt;

    out[0] = (float)all_obj;
    for (int p = 0; p < NPARTS; ++p) out[1 + p] = (float)ep[p];
    out[5] = (float)ekt;
}

extern "C" void kernel_launch(void* const* d_in, const int* in_sizes, int n_in,
                              void* d_out, int out_size, void* d_ws, size_t ws_size,
                              hipStream_t stream) {
    const float* cam  = (const float*)d_in[0];
    const float* cad  = (const float*)d_in[1];
    const float* pw   = (const float*)d_in[2];
    const float* rq   = (const float*)d_in[3];
    const float* tras = (const float*)d_in[4];
    const float* rtk  = (const float*)d_in[5];
    const float* ja   = (const float*)d_in[6];
    float* out = (float*)d_out;
    float* ws  = (float*)d_ws;

    hipLaunchKernelGGL(k_setup,   dim3(64),   dim3(256), 0, stream, rq, tras, ws, out);
    hipLaunchKernelGGL(k_chamfer, dim3(1024), dim3(256), 0, stream, cam, cad, ws);
    hipLaunchKernelGGL(k_reduce,  dim3(192),  dim3(256), 0, stream, cam, cad, ws);
    hipLaunchKernelGGL(k_final,   dim3(1),    dim3(1),   0, stream, pw, rtk, ja, ws, out);
}